// Round 1
// baseline (204.703 us; speedup 1.0000x reference)
//
#include <hip/hip_runtime.h>
#include <math.h>

#define B_ 32
#define D_ 16
#define H_ 256
#define W_ 256
#define N_ 512

// Kernel 1: gather embeddings at keypoint pixel locations.
// ebd[b][n][d] = pred[b][d][y(b,n)][x(b,n)],  y=floor(kpt0*W), x=floor(kpt1*H)
// grid: 256 blocks (8 parts per batch), 256 threads; each thread writes 4 elements.
__global__ __launch_bounds__(256) void gather_k(const float* __restrict__ pred,
                                                const float* __restrict__ kpt,
                                                float* __restrict__ ebd) {
    int bi = blockIdx.x;
    int b = bi >> 3;
    int part = bi & 7;
    int t = threadIdx.x;
#pragma unroll
    for (int j = 0; j < 4; ++j) {
        int e = part * 1024 + t + j * 256;  // element within batch: n*16+d
        int n = e >> 4;
        int d = e & 15;
        float k0 = kpt[(b * N_ + n) * 2 + 0];
        float k1 = kpt[(b * N_ + n) * 2 + 1];
        int y = (int)floorf(k0 * (float)W_);
        int x = (int)floorf(k1 * (float)H_);
        y = min(max(y, 0), H_ - 1);
        x = min(max(x, 0), W_ - 1);
        ebd[(size_t)b * (N_ * D_) + e] =
            pred[(((size_t)b * D_ + d) * H_ + y) * W_ + x];
    }
}

// Kernel 2: pairwise loss. grid = 32 batches * 8 n-tiles = 256 blocks, 256 threads.
// Each thread owns one n (4 threads per n), iterates 128 m values (m = 4i+q).
__global__ __launch_bounds__(256) void pair_k(const float* __restrict__ ebd,
                                              const int* __restrict__ vis,
                                              const int* __restrict__ tag,
                                              float* __restrict__ out) {
    __shared__ float4 es[N_ * 4];   // 512 rows x 16 floats = 32 KB
    __shared__ int tg[N_];
    __shared__ float ms[N_];
    __shared__ float racc[4], rk[4];

    int bi = blockIdx.x;
    int b = bi >> 3;
    int nt = bi & 7;
    int t = threadIdx.x;

    const float4* eg = (const float4*)(ebd + (size_t)b * (N_ * D_));
#pragma unroll
    for (int i = t; i < N_ * 4; i += 256) es[i] = eg[i];
    for (int i = t; i < N_; i += 256) {
        tg[i] = tag[b * N_ + i];
        ms[i] = (vis[b * N_ + i] > 0) ? 1.0f : 0.0f;
    }
    __syncthreads();

    // per-thread piece of K = sum(mask)
    float kpart = ms[t] + ms[t + 256];

    int n = nt * 64 + (t >> 2);
    int q = t & 3;
    float4 a0 = es[n * 4 + 0], a1 = es[n * 4 + 1];
    float4 a2 = es[n * 4 + 2], a3 = es[n * 4 + 3];
    int tn = tg[n];
    float mn = ms[n];

    float acc = 0.0f;
    for (int i = 0; i < 128; ++i) {
        int m = i * 4 + q;
        float4 b0 = es[m * 4 + 0], b1 = es[m * 4 + 1];
        float4 b2 = es[m * 4 + 2], b3 = es[m * 4 + 3];
        float s, dd;
        dd = a0.x - b0.x; s  = dd * dd;
        dd = a0.y - b0.y; s += dd * dd;
        dd = a0.z - b0.z; s += dd * dd;
        dd = a0.w - b0.w; s += dd * dd;
        dd = a1.x - b1.x; s += dd * dd;
        dd = a1.y - b1.y; s += dd * dd;
        dd = a1.z - b1.z; s += dd * dd;
        dd = a1.w - b1.w; s += dd * dd;
        dd = a2.x - b2.x; s += dd * dd;
        dd = a2.y - b2.y; s += dd * dd;
        dd = a2.z - b2.z; s += dd * dd;
        dd = a2.w - b2.w; s += dd * dd;
        dd = a3.x - b3.x; s += dd * dd;
        dd = a3.y - b3.y; s += dd * dd;
        dd = a3.z - b3.z; s += dd * dd;
        dd = a3.w - b3.w; s += dd * dd;
        float ex = s * (1.0f / 16.0f);           // mean over D=16
        float ps = 2.0f / (1.0f + __expf(ex));   // pred_sim
        float ts = (tn == tg[m]) ? 1.0f : 0.0f;  // true_sim
        float w  = (ts > 0.0f || ps > 0.0f) ? 10.0f : 0.0f;
        float di = ps - ts;
        acc += di * di * w * (mn * ms[m]);
    }

    // block reduction of acc and kpart (wave64 shuffles, then 4 waves via LDS)
#pragma unroll
    for (int off = 32; off; off >>= 1) {
        acc   += __shfl_down(acc, off);
        kpart += __shfl_down(kpart, off);
    }
    if ((t & 63) == 0) { racc[t >> 6] = acc; rk[t >> 6] = kpart; }
    __syncthreads();
    if (t == 0) {
        float tot = racc[0] + racc[1] + racc[2] + racc[3];
        float K   = rk[0] + rk[1] + rk[2] + rk[3];
        float scale = 1.0f / (fmaxf(K * K, 1.0f) * (float)B_);
        atomicAdd(out, tot * scale);
    }
}

extern "C" void kernel_launch(void* const* d_in, const int* in_sizes, int n_in,
                              void* d_out, int out_size, void* d_ws, size_t ws_size,
                              hipStream_t stream) {
    const float* pred = (const float*)d_in[0];
    const float* kpt  = (const float*)d_in[1];
    const int*   vis  = (const int*)d_in[2];
    const int*   tag  = (const int*)d_in[3];
    float* out = (float*)d_out;
    float* ebd = (float*)d_ws;  // B*N*D floats = 1 MB

    hipMemsetAsync(out, 0, sizeof(float), stream);
    gather_k<<<256, 256, 0, stream>>>(pred, kpt, ebd);
    pair_k<<<256, 256, 0, stream>>>(ebd, vis, tag, out);
}

// Round 2
// 201.855 us; speedup vs baseline: 1.0141x; 1.0141x over previous
//
#include <hip/hip_runtime.h>
#include <math.h>

#define B_ 32
#define D_ 16
#define H_ 256
#define W_ 256
#define N_ 512
#define TS 64          // tile size
#define NT 8           // tiles per dim (N_/TS)
#define NPAIR 36       // NT*(NT+1)/2 triangle tile-pairs
#define RS 20          // padded LDS row stride in floats (80B, 16B-aligned, conflict-free)

// Fused kernel: one block per (batch, triangle tile-pair).
// grid = 32 * 36 = 1152 blocks, 256 threads.
// Each block gathers its two 64-row embedding slices from pred directly into
// LDS, then computes the 64x64 pair tile; off-diagonal tiles weighted x2.
__global__ __launch_bounds__(256) void tagloss_k(const float* __restrict__ pred,
                                                 const float* __restrict__ kpt,
                                                 const int* __restrict__ vis,
                                                 const int* __restrict__ tag,
                                                 float* __restrict__ out) {
    __shared__ float eA[TS * RS];   // 5120 B
    __shared__ float eB[TS * RS];   // 5120 B
    __shared__ float sqA[TS], sqB[TS];   // mean(row^2)
    __shared__ int   tgA[TS], tgB[TS];
    __shared__ float msA[TS], msB[TS];
    __shared__ float redA[4], redK[4];

    int bi = blockIdx.x;
    int b  = bi / NPAIR;
    int p  = bi - b * NPAIR;
    // triangle decode: p -> (ti, tj), ti <= tj
    int ti = 0, rem = p;
    while (rem >= (NT - ti)) { rem -= (NT - ti); ++ti; }
    int tj = ti + rem;

    int t = threadIdx.x;

    // ---- staging: 128 rows (64 A + 64 B), 2 threads per row, 8 d-values each
    {
        int r    = t >> 1;        // 0..127
        int half = t & 1;         // which 8 channels
        int inA  = (r < TS);
        int rr   = inA ? r : (r - TS);
        int n    = (inA ? ti : tj) * TS + rr;
        float k0 = kpt[(b * N_ + n) * 2 + 0];
        float k1 = kpt[(b * N_ + n) * 2 + 1];
        int y = (int)floorf(k0 * (float)W_);
        int x = (int)floorf(k1 * (float)H_);
        y = min(max(y, 0), H_ - 1);
        x = min(max(x, 0), W_ - 1);
        const float* pb = pred + (((size_t)b * D_ + half * 8) * H_ + y) * W_ + x;
        float v[8];
#pragma unroll
        for (int dd = 0; dd < 8; ++dd) v[dd] = pb[(size_t)dd * (H_ * W_)];
        float psum = 0.f;
#pragma unroll
        for (int dd = 0; dd < 8; ++dd) psum += v[dd] * v[dd];
        float other = __shfl_xor(psum, 1);          // partner half of same row
        float sqm = (psum + other) * (1.0f / (float)D_);

        float* dst = (inA ? eA : eB) + rr * RS + half * 8;
        ((float4*)dst)[0] = make_float4(v[0], v[1], v[2], v[3]);
        ((float4*)dst)[1] = make_float4(v[4], v[5], v[6], v[7]);
        if (half == 0) {
            int   tgv = tag[b * N_ + n];
            float msv = (vis[b * N_ + n] > 0) ? 1.0f : 0.0f;
            if (inA) { sqA[rr] = sqm; tgA[rr] = tgv; msA[rr] = msv; }
            else     { sqB[rr] = sqm; tgB[rr] = tgv; msB[rr] = msv; }
        }
    }
    // per-thread piece of K = sum over full batch mask (redundant across blocks)
    float kpart = ((vis[b * N_ + t] > 0) ? 1.0f : 0.0f) +
                  ((vis[b * N_ + t + 256] > 0) ? 1.0f : 0.0f);
    __syncthreads();

    // ---- pair tile: thread owns row r2 of A-tile, quarter q of m-range
    int r2 = t >> 2;
    int q  = t & 3;
    const float4* ap = (const float4*)&eA[r2 * RS];
    float4 a0 = ap[0], a1 = ap[1], a2 = ap[2], a3 = ap[3];
    float sa = sqA[r2];
    int   tn = tgA[r2];
    float mn = msA[r2];

    float acc = 0.0f;
#pragma unroll 4
    for (int i = 0; i < 16; ++i) {
        int m = (i << 2) | q;
        const float4* bp = (const float4*)&eB[m * RS];
        float4 b0 = bp[0], b1 = bp[1], b2 = bp[2], b3 = bp[3];
        float dot;
        dot  = a0.x * b0.x; dot += a0.y * b0.y; dot += a0.z * b0.z; dot += a0.w * b0.w;
        dot += a1.x * b1.x; dot += a1.y * b1.y; dot += a1.z * b1.z; dot += a1.w * b1.w;
        dot += a2.x * b2.x; dot += a2.y * b2.y; dot += a2.z * b2.z; dot += a2.w * b2.w;
        dot += a3.x * b3.x; dot += a3.y * b3.y; dot += a3.z * b3.z; dot += a3.w * b3.w;
        float ex = sa + sqB[m] - 0.125f * dot;     // mean((a-b)^2)
        float ps = 2.0f / (1.0f + __expf(ex));     // pred_sim (always > 0 when finite)
        float ts = (tn == tgB[m]) ? 1.0f : 0.0f;   // true_sim
        float di = ps - ts;
        acc += di * di * msB[m];                   // wgt==10 hoisted to epilogue
    }
    acc *= mn;

    // ---- block reduction (wave64 shuffles, then 4 waves via LDS)
#pragma unroll
    for (int off = 32; off; off >>= 1) {
        acc   += __shfl_down(acc, off);
        kpart += __shfl_down(kpart, off);
    }
    if ((t & 63) == 0) { redA[t >> 6] = acc; redK[t >> 6] = kpart; }
    __syncthreads();
    if (t == 0) {
        float tot = redA[0] + redA[1] + redA[2] + redA[3];
        float K   = redK[0] + redK[1] + redK[2] + redK[3];
        float tilew = (ti == tj) ? 1.0f : 2.0f;    // triangle symmetry
        float scale = 10.0f * tilew / (fmaxf(K * K, 1.0f) * (float)B_);
        atomicAdd(out, tot * scale);
    }
}

extern "C" void kernel_launch(void* const* d_in, const int* in_sizes, int n_in,
                              void* d_out, int out_size, void* d_ws, size_t ws_size,
                              hipStream_t stream) {
    const float* pred = (const float*)d_in[0];
    const float* kpt  = (const float*)d_in[1];
    const int*   vis  = (const int*)d_in[2];
    const int*   tag  = (const int*)d_in[3];
    float* out = (float*)d_out;

    hipMemsetAsync(out, 0, sizeof(float) * out_size, stream);
    tagloss_k<<<B_ * NPAIR, 256, 0, stream>>>(pred, kpt, vis, tag, out);
}